// Round 1
// baseline (198.605 us; speedup 1.0000x reference)
//
#include <hip/hip_runtime.h>
#include <hip/hip_bf16.h>

#define L_SEQ    1024
#define IN_DIM   256
#define DIM_MSA  32
#define PAIR_DIM 64
#define ISPLIT   4
#define ICHUNK   (L_SEQ / ISPLIT)   // 256

// s[i][c] = b1[c] + sum_d seq[i][d] * W1[c][d]
__global__ void k_proj1(const float* __restrict__ seq, const float* __restrict__ W1,
                        const float* __restrict__ b1, float* __restrict__ s) {
    int t = blockIdx.x * blockDim.x + threadIdx.x;   // 1024*32 threads
    int i = t >> 5, c = t & 31;
    const float4* sq = (const float4*)(seq + i * IN_DIM);
    const float4* w  = (const float4*)(W1  + c * IN_DIM);
    float a0 = 0.f, a1 = 0.f, a2 = 0.f, a3 = 0.f;
#pragma unroll
    for (int d4 = 0; d4 < IN_DIM / 4; ++d4) {
        float4 x = sq[d4], y = w[d4];
        a0 += x.x * y.x;  a1 += x.y * y.y;
        a2 += x.z * y.z;  a3 += x.w * y.w;
    }
    s[t] = b1[c] + ((a0 + a1) + (a2 + a3));
}

// tmp[j][p][d] = sum_c s[j][c] * W2[p][c*32+d]   (thread computes 4 consecutive d)
__global__ void k_proj2(const float* __restrict__ s, const float* __restrict__ W2,
                        float* __restrict__ tmp) {
    int t = blockIdx.x * blockDim.x + threadIdx.x;   // 1024*64*8 threads
    int q = t & 7, p = (t >> 3) & 63, j = t >> 9;
    const float4* w  = (const float4*)W2;            // idx = p*256 + c*8 + q
    const float*  sj = s + j * DIM_MSA;
    float4 acc = {0.f, 0.f, 0.f, 0.f};
#pragma unroll
    for (int c = 0; c < DIM_MSA; ++c) {
        float  sc = sj[c];
        float4 wv = w[p * 256 + c * 8 + q];
        acc.x += sc * wv.x;  acc.y += sc * wv.y;
        acc.z += sc * wv.z;  acc.w += sc * wv.w;
    }
    ((float4*)tmp)[t] = acc;   // t = j*512 + p*8 + q  ==  [j][p][d] as float4
}

// out[i][j][p] = sum_d s[i][d]*tmp[j][p][d] + b2[p] + pair[i][j][p]
// One wave per (j, i-chunk). lane = p. tmp[j][p][:] lives in 32 VGPRs.
__global__ __launch_bounds__(256) void k_outer(
    const float* __restrict__ s, const float* __restrict__ tmp,
    const float* __restrict__ pair, const float* __restrict__ b2,
    float* __restrict__ out) {
    __shared__ float s_lds[ICHUNK * DIM_MSA];   // 32 KB

    int tid  = threadIdx.x;
    int wave = tid >> 6, lane = tid & 63;
    int jgrp  = blockIdx.x & 255;               // 256 j-groups of 4
    int chunk = blockIdx.x >> 8;                // ISPLIT chunks
    int j  = jgrp * 4 + wave;
    int i0 = chunk * ICHUNK;

    // stage s[i0 .. i0+ICHUNK) -> LDS (8192 floats, 2048 float4, 8 per thread)
    const float4* s4 = (const float4*)(s + i0 * DIM_MSA);
    float4* l4 = (float4*)s_lds;
#pragma unroll
    for (int k = 0; k < 8; ++k)
        l4[tid + 256 * k] = s4[tid + 256 * k];

    // tmp[j][lane][0..31] -> 32 VGPRs
    const float4* tj = (const float4*)(tmp + (size_t)(j * PAIR_DIM + lane) * DIM_MSA);
    float4 r0 = tj[0], r1 = tj[1], r2 = tj[2], r3 = tj[3],
           r4 = tj[4], r5 = tj[5], r6 = tj[6], r7 = tj[7];
    float bias = b2[lane];
    __syncthreads();

    const size_t stride = (size_t)L_SEQ * PAIR_DIM;              // 65536
    const float* pr = pair + ((size_t)i0 * L_SEQ + j) * PAIR_DIM + lane;
    float*       po = out  + ((size_t)i0 * L_SEQ + j) * PAIR_DIM + lane;

#pragma unroll 2
    for (int it = 0; it < ICHUNK; ++it) {
        float pv = *pr;                                          // pair (HBM)
        const float4* sv = (const float4*)(s_lds + it * DIM_MSA); // uniform -> broadcast
        float4 s0 = sv[0], s1 = sv[1], s2 = sv[2], s3 = sv[3],
               s4v = sv[4], s5 = sv[5], s6 = sv[6], s7 = sv[7];
        float a0 = s0.x*r0.x + s0.y*r0.y + s0.z*r0.z + s0.w*r0.w
                 + s1.x*r1.x + s1.y*r1.y + s1.z*r1.z + s1.w*r1.w;
        float a1 = s2.x*r2.x + s2.y*r2.y + s2.z*r2.z + s2.w*r2.w
                 + s3.x*r3.x + s3.y*r3.y + s3.z*r3.z + s3.w*r3.w;
        float a2 = s4v.x*r4.x + s4v.y*r4.y + s4v.z*r4.z + s4v.w*r4.w
                 + s5.x*r5.x + s5.y*r5.y + s5.z*r5.z + s5.w*r5.w;
        float a3 = s6.x*r6.x + s6.y*r6.y + s6.z*r6.z + s6.w*r6.w
                 + s7.x*r7.x + s7.y*r7.y + s7.z*r7.z + s7.w*r7.w;
        *po = ((a0 + a1) + (a2 + a3)) + bias + pv;
        pr += stride; po += stride;
    }
}

extern "C" void kernel_launch(void* const* d_in, const int* in_sizes, int n_in,
                              void* d_out, int out_size, void* d_ws, size_t ws_size,
                              hipStream_t stream) {
    const float* seq  = (const float*)d_in[0];   // [1,1024,256]
    const float* pair = (const float*)d_in[1];   // [1,1024,1024,64]
    const float* W1   = (const float*)d_in[2];   // [32,256]
    const float* b1   = (const float*)d_in[3];   // [32]
    const float* W2   = (const float*)d_in[4];   // [64,1024]
    const float* b2   = (const float*)d_in[5];   // [64]
    float* out = (float*)d_out;

    float* s_ws   = (float*)d_ws;                         // 1024*32   = 128 KB
    float* tmp_ws = s_ws + (size_t)L_SEQ * DIM_MSA;       // 1024*64*32 = 8 MB

    k_proj1<<<(L_SEQ * DIM_MSA) / 256, 256, 0, stream>>>(seq, W1, b1, s_ws);
    k_proj2<<<(L_SEQ * PAIR_DIM * (DIM_MSA / 4)) / 256, 256, 0, stream>>>(s_ws, W2, tmp_ws);
    k_outer<<<L_SEQ, 256, 0, stream>>>(s_ws, tmp_ws, pair, b2, out);
}

// Round 2
// 170.453 us; speedup vs baseline: 1.1652x; 1.1652x over previous
//
#include <hip/hip_runtime.h>
#include <hip/hip_bf16.h>

#define L_SEQ    1024
#define IN_DIM   256
#define DIM_MSA  32
#define PAIR_DIM 64
#define ISPLIT   8
#define ICHUNK   (L_SEQ / ISPLIT)   // 128

// s[i][c] = b1[c] + sum_d seq[i][d] * W1[c][d]
__global__ void k_proj1(const float* __restrict__ seq, const float* __restrict__ W1,
                        const float* __restrict__ b1, float* __restrict__ s) {
    int t = blockIdx.x * blockDim.x + threadIdx.x;   // 1024*32 threads
    int i = t >> 5, c = t & 31;
    const float4* sq = (const float4*)(seq + i * IN_DIM);
    const float4* w  = (const float4*)(W1  + c * IN_DIM);
    float a0 = 0.f, a1 = 0.f, a2 = 0.f, a3 = 0.f;
#pragma unroll
    for (int d4 = 0; d4 < IN_DIM / 4; ++d4) {
        float4 x = sq[d4], y = w[d4];
        a0 += x.x * y.x;  a1 += x.y * y.y;
        a2 += x.z * y.z;  a3 += x.w * y.w;
    }
    s[t] = b1[c] + ((a0 + a1) + (a2 + a3));
}

// tmp[j][p][d] = sum_c s[j][c] * W2[p][c*32+d]   (thread computes 4 consecutive d)
__global__ void k_proj2(const float* __restrict__ s, const float* __restrict__ W2,
                        float* __restrict__ tmp) {
    int t = blockIdx.x * blockDim.x + threadIdx.x;   // 1024*64*8 threads
    int q = t & 7, p = (t >> 3) & 63, j = t >> 9;
    const float4* w  = (const float4*)W2;            // idx = p*256 + c*8 + q
    const float*  sj = s + j * DIM_MSA;
    float4 acc = {0.f, 0.f, 0.f, 0.f};
#pragma unroll
    for (int c = 0; c < DIM_MSA; ++c) {
        float  sc = sj[c];
        float4 wv = w[p * 256 + c * 8 + q];
        acc.x += sc * wv.x;  acc.y += sc * wv.y;
        acc.z += sc * wv.z;  acc.w += sc * wv.w;
    }
    ((float4*)tmp)[t] = acc;   // t = j*512 + p*8 + q  ==  [j][p][d] as float4
}

// out[i][j][p] = sum_d s[i][d]*tmp[j][p][d] + b2[p] + pair[i][j][p]
// One wave per (j, i-chunk). lane = p. tmp[j][p][:] lives in 32 VGPRs.
__global__ __launch_bounds__(256, 6) void k_outer(
    const float* __restrict__ s, const float* __restrict__ tmp,
    const float* __restrict__ pair, const float* __restrict__ b2,
    float* __restrict__ out) {
    __shared__ float s_lds[ICHUNK * DIM_MSA];   // 16 KB

    int tid  = threadIdx.x;
    int wave = tid >> 6, lane = tid & 63;
    int jgrp  = blockIdx.x & 255;               // 256 j-groups of 4
    int chunk = blockIdx.x >> 8;                // ISPLIT chunks
    int j  = jgrp * 4 + wave;
    int i0 = chunk * ICHUNK;

    // stage s[i0 .. i0+ICHUNK) -> LDS (4096 floats, 1024 float4, 4 per thread)
    const float4* s4 = (const float4*)(s + i0 * DIM_MSA);
    float4* l4 = (float4*)s_lds;
#pragma unroll
    for (int k = 0; k < ICHUNK * DIM_MSA / 4 / 256; ++k)
        l4[tid + 256 * k] = s4[tid + 256 * k];

    // tmp[j][lane][0..31] -> 32 VGPRs
    const float4* tj = (const float4*)(tmp + (size_t)(j * PAIR_DIM + lane) * DIM_MSA);
    float4 r0 = tj[0], r1 = tj[1], r2 = tj[2], r3 = tj[3],
           r4 = tj[4], r5 = tj[5], r6 = tj[6], r7 = tj[7];
    float bias = b2[lane];
    __syncthreads();

    const size_t stride = (size_t)L_SEQ * PAIR_DIM;              // 65536
    const float* pr = pair + ((size_t)i0 * L_SEQ + j) * PAIR_DIM + lane;
    float*       po = out  + ((size_t)i0 * L_SEQ + j) * PAIR_DIM + lane;

    float pv = *pr;                                              // prefetch i0
#pragma unroll 2
    for (int it = 0; it < ICHUNK - 1; ++it) {
        pr += stride;
        float pv_next = *pr;                                     // prefetch i+1
        const float* sb = s_lds + it * DIM_MSA;
        const float4* sv = (const float4*)sb;
        float4 s0 = sv[0], s1 = sv[1], s2 = sv[2], s3 = sv[3];
        float a0 = s0.x*r0.x + s0.y*r0.y + s0.z*r0.z + s0.w*r0.w
                 + s1.x*r1.x + s1.y*r1.y + s1.z*r1.z + s1.w*r1.w;
        float a1 = s2.x*r2.x + s2.y*r2.y + s2.z*r2.z + s2.w*r2.w
                 + s3.x*r3.x + s3.y*r3.y + s3.z*r3.z + s3.w*r3.w;
        float4 s4v = sv[4], s5 = sv[5], s6 = sv[6], s7 = sv[7];
        float a2 = s4v.x*r4.x + s4v.y*r4.y + s4v.z*r4.z + s4v.w*r4.w
                 + s5.x*r5.x + s5.y*r5.y + s5.z*r5.z + s5.w*r5.w;
        float a3 = s6.x*r6.x + s6.y*r6.y + s6.z*r6.z + s6.w*r6.w
                 + s7.x*r7.x + s7.y*r7.y + s7.z*r7.z + s7.w*r7.w;
        __builtin_nontemporal_store(((a0 + a1) + (a2 + a3)) + bias + pv, po);
        po += stride;
        pv = pv_next;
    }
    {   // peeled last iteration (it = ICHUNK-1)
        const float4* sv = (const float4*)(s_lds + (ICHUNK - 1) * DIM_MSA);
        float4 s0 = sv[0], s1 = sv[1], s2 = sv[2], s3 = sv[3],
               s4v = sv[4], s5 = sv[5], s6 = sv[6], s7 = sv[7];
        float a0 = s0.x*r0.x + s0.y*r0.y + s0.z*r0.z + s0.w*r0.w
                 + s1.x*r1.x + s1.y*r1.y + s1.z*r1.z + s1.w*r1.w;
        float a1 = s2.x*r2.x + s2.y*r2.y + s2.z*r2.z + s2.w*r2.w
                 + s3.x*r3.x + s3.y*r3.y + s3.z*r3.z + s3.w*r3.w;
        float a2 = s4v.x*r4.x + s4v.y*r4.y + s4v.z*r4.z + s4v.w*r4.w
                 + s5.x*r5.x + s5.y*r5.y + s5.z*r5.z + s5.w*r5.w;
        float a3 = s6.x*r6.x + s6.y*r6.y + s6.z*r6.z + s6.w*r6.w
                 + s7.x*r7.x + s7.y*r7.y + s7.z*r7.z + s7.w*r7.w;
        __builtin_nontemporal_store(((a0 + a1) + (a2 + a3)) + bias + pv, po);
    }
}

extern "C" void kernel_launch(void* const* d_in, const int* in_sizes, int n_in,
                              void* d_out, int out_size, void* d_ws, size_t ws_size,
                              hipStream_t stream) {
    const float* seq  = (const float*)d_in[0];   // [1,1024,256]
    const float* pair = (const float*)d_in[1];   // [1,1024,1024,64]
    const float* W1   = (const float*)d_in[2];   // [32,256]
    const float* b1   = (const float*)d_in[3];   // [32]
    const float* W2   = (const float*)d_in[4];   // [64,1024]
    const float* b2   = (const float*)d_in[5];   // [64]
    float* out = (float*)d_out;

    float* s_ws   = (float*)d_ws;                         // 1024*32   = 128 KB
    float* tmp_ws = s_ws + (size_t)L_SEQ * DIM_MSA;       // 1024*64*32 = 8 MB

    k_proj1<<<(L_SEQ * DIM_MSA) / 256, 256, 0, stream>>>(seq, W1, b1, s_ws);
    k_proj2<<<(L_SEQ * PAIR_DIM * (DIM_MSA / 4)) / 256, 256, 0, stream>>>(s_ws, W2, tmp_ws);
    k_outer<<<256 * ISPLIT, 256, 0, stream>>>(s_ws, tmp_ws, pair, b2, out);
}

// Round 3
// 141.903 us; speedup vs baseline: 1.3996x; 1.2012x over previous
//
#include <hip/hip_runtime.h>
#include <hip/hip_bf16.h>

#define L_SEQ    1024
#define IN_DIM   256
#define DIM_MSA  32
#define PAIR_DIM 64
#define ISPLIT   16
#define ICHUNK   (L_SEQ / ISPLIT)   // 64

// s[i][c] = b1[c] + sum_d seq[i][d] * W1[c][d]
__global__ void k_proj1(const float* __restrict__ seq, const float* __restrict__ W1,
                        const float* __restrict__ b1, float* __restrict__ s) {
    int t = blockIdx.x * blockDim.x + threadIdx.x;   // 1024*32 threads
    int i = t >> 5, c = t & 31;
    const float4* sq = (const float4*)(seq + i * IN_DIM);
    const float4* w  = (const float4*)(W1  + c * IN_DIM);
    float a0 = 0.f, a1 = 0.f, a2 = 0.f, a3 = 0.f;
#pragma unroll
    for (int d4 = 0; d4 < IN_DIM / 4; ++d4) {
        float4 x = sq[d4], y = w[d4];
        a0 += x.x * y.x;  a1 += x.y * y.y;
        a2 += x.z * y.z;  a3 += x.w * y.w;
    }
    s[t] = b1[c] + ((a0 + a1) + (a2 + a3));
}

// tmp[j][p][d] = sum_c s[j][c] * W2[p][c*32+d]   (thread computes 4 consecutive d)
__global__ void k_proj2(const float* __restrict__ s, const float* __restrict__ W2,
                        float* __restrict__ tmp) {
    int t = blockIdx.x * blockDim.x + threadIdx.x;   // 1024*64*8 threads
    int q = t & 7, p = (t >> 3) & 63, j = t >> 9;
    const float4* w  = (const float4*)W2;            // idx = p*256 + c*8 + q
    const float*  sj = s + j * DIM_MSA;
    float4 acc = {0.f, 0.f, 0.f, 0.f};
#pragma unroll
    for (int c = 0; c < DIM_MSA; ++c) {
        float  sc = sj[c];
        float4 wv = w[p * 256 + c * 8 + q];
        acc.x += sc * wv.x;  acc.y += sc * wv.y;
        acc.z += sc * wv.z;  acc.w += sc * wv.w;
    }
    ((float4*)tmp)[t] = acc;   // t = j*512 + p*8 + q  ==  [j][p][d] as float4
}

// out[i][j][p] = sum_d s[i][d]*tmp[j][p][d] + b2[p] + pair[i][j][p]
// One wave per (j-pair, i-chunk). lane = p. tmp for TWO j's lives in 64 VGPRs;
// the 8 uniform LDS reads of s[i,:] amortize over 128 outputs per iteration.
__global__ __launch_bounds__(256, 4) void k_outer(
    const float* __restrict__ s, const float* __restrict__ tmp,
    const float* __restrict__ pair, const float* __restrict__ b2,
    float* __restrict__ out) {
    __shared__ float s_lds[ICHUNK * DIM_MSA];   // 8 KB

    int tid  = threadIdx.x;
    int wave = tid >> 6, lane = tid & 63;
    int jgrp  = blockIdx.x & 127;               // 128 j-groups of 8 j
    int chunk = blockIdx.x >> 7;                // ISPLIT i-chunks
    int j0 = jgrp * 8 + wave * 2;               // this wave: j0, j0+1
    int i0 = chunk * ICHUNK;

    // stage s[i0 .. i0+ICHUNK) -> LDS (2048 floats, 512 float4, 2 per thread)
    const float4* s4 = (const float4*)(s + i0 * DIM_MSA);
    float4* l4 = (float4*)s_lds;
    l4[tid]       = s4[tid];
    l4[tid + 256] = s4[tid + 256];

    // tmp[j0][lane][0..31], tmp[j0+1][lane][0..31] -> 64 VGPRs
    const float4* t0 = (const float4*)(tmp + (size_t)(j0 * PAIR_DIM + lane) * DIM_MSA);
    const float4* t1 = (const float4*)(tmp + (size_t)((j0 + 1) * PAIR_DIM + lane) * DIM_MSA);
    float4 r0[8], r1[8];
#pragma unroll
    for (int q = 0; q < 8; ++q) { r0[q] = t0[q]; r1[q] = t1[q]; }
    float bias = b2[lane];
    __syncthreads();

    const size_t stride = (size_t)L_SEQ * PAIR_DIM;              // 65536
    const float* pr = pair + ((size_t)i0 * L_SEQ + j0) * PAIR_DIM + lane;
    float*       po = out  + ((size_t)i0 * L_SEQ + j0) * PAIR_DIM + lane;

    float pv0 = pr[0], pv1 = pr[PAIR_DIM];                       // prefetch i0
#pragma unroll 2
    for (int it = 0; it < ICHUNK - 1; ++it) {
        pr += stride;
        float nv0 = pr[0], nv1 = pr[PAIR_DIM];                   // prefetch i+1
        float4 sr[8];
        const float4* sv = (const float4*)(s_lds + it * DIM_MSA);
#pragma unroll
        for (int q = 0; q < 8; ++q) sr[q] = sv[q];
        float a0 = 0.f, a1 = 0.f, a2 = 0.f, a3 = 0.f;
        float c0 = 0.f, c1 = 0.f, c2 = 0.f, c3 = 0.f;
#pragma unroll
        for (int q = 0; q < 8; ++q) {
            float4 sq = sr[q];
            a0 += sq.x * r0[q].x;  a1 += sq.y * r0[q].y;
            a2 += sq.z * r0[q].z;  a3 += sq.w * r0[q].w;
            c0 += sq.x * r1[q].x;  c1 += sq.y * r1[q].y;
            c2 += sq.z * r1[q].z;  c3 += sq.w * r1[q].w;
        }
        __builtin_nontemporal_store(((a0 + a1) + (a2 + a3)) + bias + pv0, po);
        __builtin_nontemporal_store(((c0 + c1) + (c2 + c3)) + bias + pv1, po + PAIR_DIM);
        po += stride;
        pv0 = nv0; pv1 = nv1;
    }
    {   // peeled last iteration (it = ICHUNK-1)
        float4 sr[8];
        const float4* sv = (const float4*)(s_lds + (ICHUNK - 1) * DIM_MSA);
#pragma unroll
        for (int q = 0; q < 8; ++q) sr[q] = sv[q];
        float a0 = 0.f, a1 = 0.f, a2 = 0.f, a3 = 0.f;
        float c0 = 0.f, c1 = 0.f, c2 = 0.f, c3 = 0.f;
#pragma unroll
        for (int q = 0; q < 8; ++q) {
            float4 sq = sr[q];
            a0 += sq.x * r0[q].x;  a1 += sq.y * r0[q].y;
            a2 += sq.z * r0[q].z;  a3 += sq.w * r0[q].w;
            c0 += sq.x * r1[q].x;  c1 += sq.y * r1[q].y;
            c2 += sq.z * r1[q].z;  c3 += sq.w * r1[q].w;
        }
        __builtin_nontemporal_store(((a0 + a1) + (a2 + a3)) + bias + pv0, po);
        __builtin_nontemporal_store(((c0 + c1) + (c2 + c3)) + bias + pv1, po + PAIR_DIM);
    }
}

extern "C" void kernel_launch(void* const* d_in, const int* in_sizes, int n_in,
                              void* d_out, int out_size, void* d_ws, size_t ws_size,
                              hipStream_t stream) {
    const float* seq  = (const float*)d_in[0];   // [1,1024,256]
    const float* pair = (const float*)d_in[1];   // [1,1024,1024,64]
    const float* W1   = (const float*)d_in[2];   // [32,256]
    const float* b1   = (const float*)d_in[3];   // [32]
    const float* W2   = (const float*)d_in[4];   // [64,1024]
    const float* b2   = (const float*)d_in[5];   // [64]
    float* out = (float*)d_out;

    float* s_ws   = (float*)d_ws;                         // 1024*32   = 128 KB
    float* tmp_ws = s_ws + (size_t)L_SEQ * DIM_MSA;       // 1024*64*32 = 8 MB

    k_proj1<<<(L_SEQ * DIM_MSA) / 256, 256, 0, stream>>>(seq, W1, b1, s_ws);
    k_proj2<<<(L_SEQ * PAIR_DIM * (DIM_MSA / 4)) / 256, 256, 0, stream>>>(s_ws, W2, tmp_ws);
    k_outer<<<128 * ISPLIT, 256, 0, stream>>>(s_ws, tmp_ws, pair, b2, out);
}